// Round 7
// baseline (698.665 us; speedup 1.0000x reference)
//
#include <hip/hip_runtime.h>
#include <stdint.h>

#define B    512
#define N    50257
#define BLK  512
#define NWAVE 8
#define TILE 6144            // stage 48 KB; total LDS ~54.3 KB -> 3 blocks/CU
#define CHUNK 768            // per-wave contiguous chunk = TILE/NWAVE
#define NGRP 12              // 64-elem groups per chunk
#define THRESH 0.4f

// Softmax weights are strictly positive floats: raw bit pattern is monotone
// in value. Complement -> ascending stable order == descending weight order,
// ties broken by ascending original index (stable LSD radix), matching
// jnp.argsort(-weights).
__device__ __forceinline__ uint32_t sort_key(float w) { return ~__float_as_uint(w); }

__device__ __forceinline__ void hist_elem(uint32_t* hw0, const float w) {
    const uint32_t key = sort_key(w);
    atomicAdd(hw0 + (key & 255u), 1u);
    atomicAdd(hw0 + 256 + ((key >> 8) & 255u), 1u);
    atomicAdd(hw0 + 512 + ((key >> 16) & 255u), 1u);
    atomicAdd(hw0 + 768 + ((key >> 24) & 255u), 1u);
}

// ---------------------------------------------------------------------------
// Shared: histogram kernel (per-wave-private bins, plain LDS atomics,
// float4-vectorized sweep).
// ---------------------------------------------------------------------------
__global__ __launch_bounds__(BLK) void hist4_fast(const float* __restrict__ wts,
                                                  uint32_t* __restrict__ histWS) {
    __shared__ uint32_t hw[NWAVE][4][256];   // 32 KB
    __shared__ uint32_t wtot[4];
    const int row = blockIdx.x;
    const size_t base = (size_t)row * N;
    const int tid = threadIdx.x;
    const int lane = tid & 63;
    const int wv = tid >> 6;

    {   // zero own wave's slice (no cross-wave access -> no barrier needed)
        uint32_t* p = &hw[wv][0][0];
        for (int j = lane; j < 4 * 256; j += 64) p[j] = 0;
    }
    uint32_t* hw0 = &hw[wv][0][0];

    // vectorized sweep (order-independent): head to 16B alignment, f4 body, tail
    const int head = (int)((4 - (base & 3)) & 3);
    for (int i = tid; i < head; i += BLK) hist_elem(hw0, wts[base + i]);
    const int nvec = (N - head) >> 2;
    const float4* v4 = (const float4*)(wts + base + head);
    for (int iv = tid; iv < nvec; iv += BLK) {
        const float4 f = v4[iv];
        hist_elem(hw0, f.x); hist_elem(hw0, f.y);
        hist_elem(hw0, f.z); hist_elem(hw0, f.w);
    }
    for (int i = head + 4 * nvec + tid; i < N; i += BLK) hist_elem(hw0, wts[base + i]);
    __syncthreads();

    for (int p = 0; p < 4; ++p) {
        uint32_t cnt = 0;
        if (tid < 256) {
            #pragma unroll
            for (int w = 0; w < NWAVE; ++w) cnt += hw[w][p][tid];
        }
        // exclusive scan over 256 bins: intra-wave shfl + cross-wave via wtot
        uint32_t incl = cnt;
        #pragma unroll
        for (int o = 1; o < 64; o <<= 1) {
            const uint32_t u = __shfl_up(incl, o);
            if (lane >= o) incl += u;
        }
        if (tid < 256 && lane == 63) wtot[tid >> 6] = incl;
        __syncthreads();
        if (tid < 256) {
            uint32_t prefix = 0;
            const int w4 = tid >> 6;
            #pragma unroll
            for (int w2 = 0; w2 < 4; ++w2) if (w2 < w4) prefix += wtot[w2];
            histWS[((size_t)row * 4 + p) * 256 + tid] = prefix + incl - cnt;
        }
        __syncthreads();   // protect wtot reuse
    }
}

// ---------------------------------------------------------------------------
// TIER A: software-pipelined wave-private scatter on packed u64 (key<<16|idx).
// TILE=6144 + u16 waveCnt keep LDS ~54.3 KB -> 3 blocks/CU (6 waves/EU).
// Prefetch for tile t+1 issues AFTER the layout barrier (round-5 proven spot;
// issuing earlier measurably broke L2/L3 producer->consumer reuse, r6).
// ---------------------------------------------------------------------------
template <int SHIFT, bool FIRST, bool LAST>
__global__ __launch_bounds__(BLK, 6) void scatter_pl(const float* __restrict__ wts,
                                                     const unsigned long long* __restrict__ src,
                                                     unsigned long long* __restrict__ dst,
                                                     uint32_t* __restrict__ outIdx,
                                                     float* __restrict__ outW,
                                                     const uint32_t* __restrict__ histWS) {
    __shared__ __align__(16) unsigned long long stage[TILE];  // 48 KB
    __shared__ uint16_t waveCnt[NWAVE][256];                  //  4 KB
    __shared__ uint32_t delta[256];                           //  1 KB
    __shared__ uint32_t wtot[4];

    const int row = blockIdx.x;
    const size_t base = (size_t)row * N;
    const int tid  = threadIdx.x;
    const int lane = tid & 63;
    const int wv   = tid >> 6;
    constexpr int PASS = SHIFT / 8;
    constexpr int KS = SHIFT + 16;   // digit position within packed pair

    uint32_t curReg = 0;             // this thread's bucket cursor (tid<256)
    if (tid < 256) curReg = histWS[((size_t)row * 4 + PASS) * 256 + tid];

    const int numTiles = (N + TILE - 1) / TILE;

    unsigned long long pairN[NGRP];
    {   // prefetch tile 0 (always full: TILE < N)
        const int cb = wv * CHUNK;
        #pragma unroll
        for (int g = 0; g < NGRP; ++g) {
            const int i = cb + g * 64 + lane;
            pairN[g] = FIRST ? (((unsigned long long)sort_key(wts[base + i]) << 16) | (uint32_t)i)
                             : src[base + i];
        }
    }

    for (int t = 0; t < numTiles; ++t) {
        const int tbase = t * TILE;
        const int tileLen = (N - tbase < TILE) ? (N - tbase) : TILE;
        const int cbase = tbase + wv * CHUNK;
        const bool full = (tbase + TILE <= N);

        // ---- Phase 1: rank own chunk from registers (NO barriers) ----
        // Safe to zero own waveCnt row here: phase 2 of tile t-1 finished
        // reading all rows before barrier (C,t-1) < (D,t-1).
        {   // 256 u16 = 512 B = 64 lanes x 8 B
            uint2* z = (uint2*)&waveCnt[wv][0];
            z[lane] = make_uint2(0u, 0u);
        }
        unsigned long long pairR[NGRP];
        uint32_t posR[NGRP];
        #pragma unroll
        for (int g = 0; g < NGRP; ++g) pairR[g] = pairN[g];

        if (full) {
            #pragma unroll
            for (int g = 0; g < NGRP; ++g) {
                const uint32_t d = (uint32_t)(pairR[g] >> KS) & 255u;
                unsigned long long peers = ~0ull;
                #pragma unroll
                for (int bb = 0; bb < 8; ++bb) {
                    const unsigned long long bit = __ballot((d >> bb) & 1u);
                    peers &= ((d >> bb) & 1u) ? bit : ~bit;
                }
                const unsigned long long lower = peers & ((1ull << lane) - 1ull);
                const uint32_t cnt = (uint32_t)waveCnt[wv][d];
                posR[g] = cnt + (uint32_t)__popcll(lower);
                if (lower == 0ull) waveCnt[wv][d] = (uint16_t)(cnt + (uint32_t)__popcll(peers));
            }
        } else {
            #pragma unroll
            for (int g = 0; g < NGRP; ++g) {
                const int i = cbase + g * 64 + lane;
                const bool valid = (i < N);
                const uint32_t d = (uint32_t)(pairR[g] >> KS) & 255u;
                unsigned long long peers = __ballot(valid);
                #pragma unroll
                for (int bb = 0; bb < 8; ++bb) {
                    const unsigned long long bit = __ballot((d >> bb) & 1u);
                    peers &= ((d >> bb) & 1u) ? bit : ~bit;
                }
                const unsigned long long lower = peers & ((1ull << lane) - 1ull);
                uint32_t cnt = 0;
                if (valid) cnt = (uint32_t)waveCnt[wv][d];
                posR[g] = cnt + (uint32_t)__popcll(lower);
                if (valid && lower == 0ull) waveCnt[wv][d] = (uint16_t)(cnt + (uint32_t)__popcll(peers));
            }
        }
        __syncthreads();                               // (A) ranks done; stage(t-1) drained

        // ---- Phase 2: tile layout (shfl scan, 2 barriers) ----
        uint32_t run = 0;
        if (tid < 256) {
            #pragma unroll
            for (int w = 0; w < NWAVE; ++w) {
                const uint32_t c = (uint32_t)waveCnt[w][tid];
                waveCnt[w][tid] = (uint16_t)run;       // excl offset across waves
                run += c;
            }
        }
        uint32_t incl = run;
        #pragma unroll
        for (int o = 1; o < 64; o <<= 1) {
            const uint32_t u = __shfl_up(incl, o);
            if (lane >= o) incl += u;
        }
        if (tid < 256 && lane == 63) wtot[tid >> 6] = incl;
        __syncthreads();                               // (B)
        if (tid < 256) {
            uint32_t prefix = 0;
            const int w4 = tid >> 6;
            #pragma unroll
            for (int w2 = 0; w2 < 4; ++w2) if (w2 < w4) prefix += wtot[w2];
            const uint32_t ts = prefix + incl - run;   // tileStart[tid]
            delta[tid] = curReg - ts;                  // global = delta[d] + p
            curReg += run;
            #pragma unroll
            for (int w = 0; w < NWAVE; ++w)
                waveCnt[w][tid] = (uint16_t)((uint32_t)waveCnt[w][tid] + ts);
        }
        __syncthreads();                               // (C) layout ready

        // ---- Prefetch next tile (latency hides under phases 3-4) ----
        if (t + 1 < numTiles) {
            const int ncb = (t + 1) * TILE + wv * CHUNK;
            if (ncb + CHUNK <= N) {                    // wave-uniform branch
                #pragma unroll
                for (int g = 0; g < NGRP; ++g) {
                    const int i = ncb + g * 64 + lane;
                    pairN[g] = FIRST ? (((unsigned long long)sort_key(wts[base + i]) << 16) | (uint32_t)i)
                                     : src[base + i];
                }
            } else {
                #pragma unroll
                for (int g = 0; g < NGRP; ++g) {
                    const int i = ncb + g * 64 + lane;
                    unsigned long long pair = 0;
                    if (i < N)
                        pair = FIRST ? (((unsigned long long)sort_key(wts[base + i]) << 16) | (uint32_t)i)
                                     : src[base + i];
                    pairN[g] = pair;
                }
            }
        }

        // ---- Phase 3: stage bucket-contiguous in LDS ----
        if (full) {
            #pragma unroll
            for (int g = 0; g < NGRP; ++g) {
                const uint32_t d = (uint32_t)(pairR[g] >> KS) & 255u;
                stage[(uint32_t)waveCnt[wv][d] + posR[g]] = pairR[g];
            }
        } else {
            #pragma unroll
            for (int g = 0; g < NGRP; ++g) {
                const int i = cbase + g * 64 + lane;
                if (i < N) {
                    const uint32_t d = (uint32_t)(pairR[g] >> KS) & 255u;
                    stage[(uint32_t)waveCnt[wv][d] + posR[g]] = pairR[g];
                }
            }
        }
        __syncthreads();                               // (D) stage complete

        // ---- Phase 4: 2-wide flush of contiguous runs to global ----
        const int tileLenEven = tileLen & ~1;
        for (int p0 = 2 * tid; p0 < tileLenEven; p0 += 2 * BLK) {
            const ulonglong2 two = *(const ulonglong2*)&stage[p0];   // 16B aligned
            const uint32_t d0 = (uint32_t)(two.x >> KS) & 255u;
            const uint32_t d1 = (uint32_t)(two.y >> KS) & 255u;
            const uint32_t g0 = delta[d0] + (uint32_t)p0;
            const uint32_t g1 = delta[d1] + (uint32_t)p0 + 1u;
            if (LAST) {
                outIdx[base + g0] = (uint32_t)(two.x & 0xFFFFull);
                outW[base + g0]   = __uint_as_float(~(uint32_t)(two.x >> 16));
                outIdx[base + g1] = (uint32_t)(two.y & 0xFFFFull);
                outW[base + g1]   = __uint_as_float(~(uint32_t)(two.y >> 16));
            } else {
                dst[base + g0] = two.x;
                dst[base + g1] = two.y;
            }
        }
        for (int p = tileLenEven + tid; p < tileLen; p += BLK) {     // odd tail
            const unsigned long long pair = stage[p];
            const uint32_t d = (uint32_t)(pair >> KS) & 255u;
            const uint32_t g = delta[d] + (uint32_t)p;
            if (LAST) {
                outIdx[base + g] = (uint32_t)(pair & 0xFFFFull);
                outW[base + g]   = __uint_as_float(~(uint32_t)(pair >> 16));
            } else {
                dst[base + g] = pair;
            }
        }
        // no trailing barrier: (A) of the next tile separates flush(t) reads
        // from stage(t+1) writes and delta(t+1) updates.
    }
}

// ---------------------------------------------------------------------------
// Shared: merged scan + normalize + idx->float (in place), block per row.
// out0 holds u32 idx, out1 holds sorted w on entry.
// ---------------------------------------------------------------------------
__global__ __launch_bounds__(BLK) void finalize_row(float* __restrict__ out0,
                                                    float* __restrict__ out1,
                                                    float* __restrict__ out2) {
    __shared__ float waveSum[NWAVE];
    __shared__ int   waveFirst[NWAVE];
    __shared__ float waveCum[NWAVE];
    __shared__ int   s_k;
    __shared__ float s_total;

    const int row = blockIdx.x;
    const size_t base = (size_t)row * N;
    const int tid  = threadIdx.x;
    const int lane = tid & 63;
    const int wv   = tid >> 6;

    if (tid == 0) { s_k = -1; s_total = 0.f; }
    __syncthreads();

    // Phase A: block-wide running cumsum with early exit
    float carry = 0.f;
    const int numTiles = (N + BLK - 1) / BLK;
    for (int t = 0; t < numTiles; ++t) {
        const int i = t * BLK + tid;
        const bool valid = (i < N);
        float w = valid ? out1[base + i] : 0.f;

        float s = w;
        #pragma unroll
        for (int o = 1; o < 64; o <<= 1) {
            float u = __shfl_up(s, o);
            if (lane >= o) s += u;
        }
        if (lane == 63) waveSum[wv] = s;
        __syncthreads();

        float prefix = 0.f, blockTot = 0.f;
        #pragma unroll
        for (int w2 = 0; w2 < NWAVE; ++w2) {
            float t2 = waveSum[w2];
            if (w2 < wv) prefix += t2;
            blockTot += t2;
        }
        const float cum = carry + prefix + s;

        const bool exceed = valid && (cum > THRESH);
        const unsigned long long bal = __ballot(exceed);
        const int fl = (bal == 0ull) ? 64 : (__ffsll(bal) - 1);
        if (lane == 0) waveFirst[wv] = fl;
        if (fl < 64 && lane == fl) waveCum[wv] = cum;
        __syncthreads();
        if (tid == 0) {
            for (int w2 = 0; w2 < NWAVE; ++w2) {
                if (waveFirst[w2] < 64) {
                    s_k = t * BLK + w2 * 64 + waveFirst[w2] + 1;
                    s_total = waveCum[w2];
                    break;
                }
            }
        }
        __syncthreads();
        if (s_k >= 0) break;
        carry += blockTot;
        __syncthreads();
    }

    int k = s_k;
    float total = s_total;
    if (k < 0) { k = N; total = carry; }
    const float inv = 1.0f / total;

    // Phase B: in-place convert + normalize, vectorized 16B (per-thread
    // read-before-write on identical addresses -> safe).
    const uint32_t* idxU = (const uint32_t*)out0;
    const int head = (int)((4 - (base & 3)) & 3);     // to 16B alignment
    const int nvec = (N - head) >> 2;
    const int vend = head + 4 * nvec;

    for (int i = tid; i < head; i += BLK) {           // head (<4 elems)
        const uint32_t idx = idxU[base + i];
        const float w = out1[base + i];
        out0[base + i] = (float)idx;
        out1[base + i] = (i < k) ? (w * inv) : 0.f;
    }
    const uint4*  ivp = (const uint4*)(idxU + base + head);
    float4*       o0v = (float4*)(out0 + base + head);
    float4*       o1v = (float4*)(out1 + base + head);
    for (int v = tid; v < nvec; v += BLK) {
        const uint4  iv = ivp[v];
        const float4 wv4 = o1v[v];
        const int i = head + 4 * v;
        float4 o0, o1;
        o0.x = (float)iv.x; o0.y = (float)iv.y; o0.z = (float)iv.z; o0.w = (float)iv.w;
        o1.x = (i + 0 < k) ? wv4.x * inv : 0.f;
        o1.y = (i + 1 < k) ? wv4.y * inv : 0.f;
        o1.z = (i + 2 < k) ? wv4.z * inv : 0.f;
        o1.w = (i + 3 < k) ? wv4.w * inv : 0.f;
        o0v[v] = o0;
        o1v[v] = o1;
    }
    for (int i = vend + tid; i < N; i += BLK) {       // tail (<4 elems)
        const uint32_t idx = idxU[base + i];
        const float w = out1[base + i];
        out0[base + i] = (float)idx;
        out1[base + i] = (i < k) ? (w * inv) : 0.f;
    }
    if (tid == 0) out2[row] = (float)k;
}

// ---------------------------------------------------------------------------
// TIER B (round-3 proven): subtile-ballot scatter on separate key/idx arrays.
// ---------------------------------------------------------------------------
#define NSUB (TILE / BLK)   // 12

template <int SHIFT, bool FIRST, bool LAST>
__global__ __launch_bounds__(BLK, 4) void scatter_tile(const float* __restrict__ wts,
                                                       const uint32_t* __restrict__ keySrc,
                                                       const uint16_t* __restrict__ idxSrc,
                                                       uint32_t* __restrict__ keyDst,
                                                       uint16_t* __restrict__ idxDst,
                                                       uint32_t* __restrict__ outIdx,
                                                       float* __restrict__ outW,
                                                       const uint32_t* __restrict__ histWS) {
    __shared__ uint32_t stageKey[TILE];
    __shared__ uint16_t stageIdx[TILE];
    __shared__ uint32_t waveCnt32[NWAVE][256];
    __shared__ uint16_t subOff[NSUB][256];
    __shared__ uint32_t cursor[256];
    __shared__ uint32_t tileCnt[256];
    __shared__ uint32_t tileStart[256];
    __shared__ uint32_t scanb[256];

    const int row = blockIdx.x;
    const size_t base = (size_t)row * N;
    const int tid  = threadIdx.x;
    const int lane = tid & 63;
    const int wv   = tid >> 6;
    constexpr int PASS = SHIFT / 8;

    if (tid < 256) cursor[tid] = histWS[((size_t)row * 4 + PASS) * 256 + tid];

    const int numTiles = (N + TILE - 1) / TILE;
    for (int t = 0; t < numTiles; ++t) {
        const int tbase = t * TILE;
        const int tileLen = (N - tbase < TILE) ? (N - tbase) : TILE;

        uint32_t keyR[NSUB];
        uint32_t idxR[NSUB];
        uint32_t posR[NSUB];

        #pragma unroll
        for (int s = 0; s < NSUB; ++s) {
            for (int j = tid; j < NWAVE * 256; j += BLK) ((uint32_t*)waveCnt32)[j] = 0;
            __syncthreads();

            const int i = tbase + s * BLK + tid;
            const bool valid = (i < N);
            uint32_t key = 0, idx = 0, d = 0;
            if (valid) {
                if (FIRST) { key = sort_key(wts[base + i]); idx = (uint32_t)i; }
                else       { key = keySrc[base + i]; idx = (uint32_t)idxSrc[base + i]; }
                d = (key >> SHIFT) & 255u;
            }
            keyR[s] = key;
            if (!FIRST) idxR[s] = idx;

            unsigned long long peers = __ballot(valid);
            #pragma unroll
            for (int b = 0; b < 8; ++b) {
                unsigned long long bit = __ballot(valid && ((d >> b) & 1u));
                peers &= ((d >> b) & 1u) ? bit : ~bit;
            }
            const unsigned long long lower = peers & ((1ull << lane) - 1ull);
            const uint32_t rank = (uint32_t)__popcll(lower);
            if (valid && lower == 0ull) waveCnt32[wv][d] = (uint32_t)__popcll(peers);
            __syncthreads();

            if (tid < 256) {
                uint32_t x = 0;
                #pragma unroll
                for (int w = 0; w < NWAVE; ++w) {
                    uint32_t c = waveCnt32[w][tid];
                    waveCnt32[w][tid] = x;
                    x += c;
                }
                subOff[s][tid] = (uint16_t)x;
            }
            __syncthreads();

            posR[s] = valid ? (waveCnt32[wv][d] + rank) : 0u;
            __syncthreads();
        }

        if (tid < 256) {
            uint32_t run = 0;
            #pragma unroll
            for (int s = 0; s < NSUB; ++s) {
                uint32_t c = subOff[s][tid];
                subOff[s][tid] = (uint16_t)run;
                run += c;
            }
            tileCnt[tid] = run;
            scanb[tid] = run;
        }
        __syncthreads();
        for (int off = 1; off < 256; off <<= 1) {
            uint32_t add = 0;
            if (tid < 256 && tid >= off) add = scanb[tid - off];
            __syncthreads();
            if (tid < 256) scanb[tid] += add;
            __syncthreads();
        }
        if (tid < 256) tileStart[tid] = (tid == 0) ? 0u : scanb[tid - 1];
        __syncthreads();

        #pragma unroll
        for (int s = 0; s < NSUB; ++s) {
            const int i = tbase + s * BLK + tid;
            if (i < N) {
                const uint32_t d = (keyR[s] >> SHIFT) & 255u;
                const uint32_t pos = tileStart[d] + (uint32_t)subOff[s][d] + posR[s];
                stageKey[pos] = keyR[s];
                stageIdx[pos] = (uint16_t)(FIRST ? (uint32_t)i : idxR[s]);
            }
        }
        __syncthreads();

        for (int p = tid; p < tileLen; p += BLK) {
            const uint32_t k = stageKey[p];
            const uint32_t d = (k >> SHIFT) & 255u;
            const uint32_t g = cursor[d] + (uint32_t)p - tileStart[d];
            if (LAST) {
                outIdx[base + g] = (uint32_t)stageIdx[p];
                outW[base + g]   = __uint_as_float(~k);
            } else {
                keyDst[base + g] = k;
                idxDst[base + g] = stageIdx[p];
            }
        }
        __syncthreads();
        if (tid < 256) cursor[tid] += tileCnt[tid];
        __syncthreads();
    }
}

// ---------------------------------------------------------------------------
// TIER C (round-1 proven): gather-based fallback, no workspace.
// ---------------------------------------------------------------------------
template <int SHIFT>
__global__ __launch_bounds__(BLK) void radix_pass_fb(const float* __restrict__ wts,
                                                     const uint32_t* __restrict__ src,
                                                     uint32_t* __restrict__ dst) {
    __shared__ uint32_t hist[256];
    __shared__ uint32_t scanb[256];
    __shared__ uint32_t running[256];
    __shared__ uint32_t waveCnt32[NWAVE][256];

    const int row = blockIdx.x;
    const size_t base = (size_t)row * N;
    const int tid  = threadIdx.x;
    const int lane = tid & 63;
    const int wv   = tid >> 6;

    if (tid < 256) hist[tid] = 0;
    __syncthreads();
    for (int i = tid; i < N; i += BLK) {
        uint32_t idx = (SHIFT == 0) ? (uint32_t)i : src[base + i];
        uint32_t d = (sort_key(wts[base + idx]) >> SHIFT) & 255u;
        atomicAdd(&hist[d], 1u);
    }
    __syncthreads();

    if (tid < 256) scanb[tid] = hist[tid];
    __syncthreads();
    for (int off = 1; off < 256; off <<= 1) {
        uint32_t add = 0;
        if (tid < 256 && tid >= off) add = scanb[tid - off];
        __syncthreads();
        if (tid < 256) scanb[tid] += add;
        __syncthreads();
    }
    if (tid < 256) running[tid] = (tid == 0) ? 0u : scanb[tid - 1];
    __syncthreads();

    const int numTiles = (N + BLK - 1) / BLK;
    for (int t = 0; t < numTiles; ++t) {
        for (int j = tid; j < NWAVE * 256; j += BLK) ((uint32_t*)waveCnt32)[j] = 0;
        __syncthreads();

        const int i = t * BLK + tid;
        const bool valid = (i < N);
        uint32_t idx = 0, d = 0;
        if (valid) {
            idx = (SHIFT == 0) ? (uint32_t)i : src[base + i];
            d = (sort_key(wts[base + idx]) >> SHIFT) & 255u;
        }
        unsigned long long peers = __ballot(valid);
        #pragma unroll
        for (int b = 0; b < 8; ++b) {
            unsigned long long bit = __ballot(valid && ((d >> b) & 1u));
            peers &= ((d >> b) & 1u) ? bit : ~bit;
        }
        const unsigned long long lower = peers & ((1ull << lane) - 1ull);
        const uint32_t rank = (uint32_t)__popcll(lower);
        if (valid && lower == 0ull) waveCnt32[wv][d] = (uint32_t)__popcll(peers);
        __syncthreads();

        if (tid < 256) {
            uint32_t s = running[tid];
            #pragma unroll
            for (int w = 0; w < NWAVE; ++w) {
                uint32_t c = waveCnt32[w][tid];
                waveCnt32[w][tid] = s;
                s += c;
            }
            running[tid] = s;
        }
        __syncthreads();

        if (valid) {
            uint32_t pos = waveCnt32[wv][d] + rank;
            dst[base + pos] = idx;
        }
        __syncthreads();
    }
}

__global__ __launch_bounds__(BLK) void finalize_fb(const float* __restrict__ wts,
                                                   const uint32_t* __restrict__ sidx,
                                                   float* __restrict__ out0,
                                                   float* __restrict__ out1,
                                                   float* __restrict__ out2) {
    __shared__ float waveSum[NWAVE];
    __shared__ int   waveFirst[NWAVE];
    __shared__ float waveCum[NWAVE];
    __shared__ int   s_k;
    __shared__ float s_total;

    const int row = blockIdx.x;
    const size_t base = (size_t)row * N;
    const int tid  = threadIdx.x;
    const int lane = tid & 63;
    const int wv   = tid >> 6;

    if (tid == 0) { s_k = -1; s_total = 0.f; }
    __syncthreads();

    float carry = 0.f;
    const int numTiles = (N + BLK - 1) / BLK;
    for (int t = 0; t < numTiles; ++t) {
        const int i = t * BLK + tid;
        const bool valid = (i < N);
        float w = valid ? wts[base + sidx[base + i]] : 0.f;

        float s = w;
        #pragma unroll
        for (int o = 1; o < 64; o <<= 1) {
            float u = __shfl_up(s, o);
            if (lane >= o) s += u;
        }
        if (lane == 63) waveSum[wv] = s;
        __syncthreads();

        float prefix = 0.f, blockTot = 0.f;
        #pragma unroll
        for (int w2 = 0; w2 < NWAVE; ++w2) {
            float t2 = waveSum[w2];
            if (w2 < wv) prefix += t2;
            blockTot += t2;
        }
        const float cum = carry + prefix + s;

        const bool exceed = valid && (cum > THRESH);
        const unsigned long long bal = __ballot(exceed);
        const int fl = (bal == 0ull) ? 64 : (__ffsll(bal) - 1);
        if (lane == 0) waveFirst[wv] = fl;
        if (fl < 64 && lane == fl) waveCum[wv] = cum;
        __syncthreads();
        if (tid == 0) {
            for (int w2 = 0; w2 < NWAVE; ++w2) {
                if (waveFirst[w2] < 64) {
                    s_k = t * BLK + w2 * 64 + waveFirst[w2] + 1;
                    s_total = waveCum[w2];
                    break;
                }
            }
        }
        __syncthreads();
        if (s_k >= 0) break;
        carry += blockTot;
        __syncthreads();
    }

    int k = s_k;
    float total = s_total;
    if (k < 0) { k = N; total = carry; }

    for (int i = tid; i < N; i += BLK) {
        const uint32_t idx = sidx[base + i];
        const float w = wts[base + idx];
        out0[base + i] = (float)idx;
        out1[base + i] = (i < k) ? (w / total) : 0.f;
    }
    if (tid == 0) out2[row] = (float)k;
}

// ---------------------------------------------------------------------------

extern "C" void kernel_launch(void* const* d_in, const int* in_sizes, int n_in,
                              void* d_out, int out_size, void* d_ws, size_t ws_size,
                              hipStream_t stream) {
    const float* wts = (const float*)d_in[0];
    float* out0 = (float*)d_out;                       // sorted_idx (as f32)
    float* out1 = out0 + (size_t)B * N;                // norm_w
    float* out2 = out0 + 2 * (size_t)B * N;            // k (as f32)

    const size_t PAIR_BYTES = (size_t)B * N * 8;       // 205,852,672
    const size_t KEY_BYTES  = (size_t)B * N * 4;
    const size_t IDX_BYTES  = (size_t)B * N * 2;
    const size_t HIST_BYTES = (size_t)B * 4 * 256 * 4; // 2,097,152
    const size_t WS_A = PAIR_BYTES + HIST_BYTES;
    const size_t WS_B = KEY_BYTES + IDX_BYTES + HIST_BYTES;

    dim3 g(B), b(BLK);
    if (ws_size >= WS_A) {
        // Tier A: pipelined packed-u64 wave-private path.
        uint8_t* ws = (uint8_t*)d_ws;
        unsigned long long* pairWS  = (unsigned long long*)ws;
        uint32_t*           histWS  = (uint32_t*)(ws + PAIR_BYTES);
        unsigned long long* pairOUT = (unsigned long long*)d_out;  // 206MB in d_out

        hist4_fast<<<g, b, 0, stream>>>(wts, histWS);
        scatter_pl<0,  true,  false><<<g, b, 0, stream>>>(wts, nullptr, pairWS, nullptr, nullptr, histWS);
        scatter_pl<8,  false, false><<<g, b, 0, stream>>>(nullptr, pairWS, pairOUT, nullptr, nullptr, histWS);
        scatter_pl<16, false, false><<<g, b, 0, stream>>>(nullptr, pairOUT, pairWS, nullptr, nullptr, histWS);
        scatter_pl<24, false, true ><<<g, b, 0, stream>>>(nullptr, pairWS, nullptr, (uint32_t*)out0, out1, histWS);
        finalize_row<<<g, b, 0, stream>>>(out0, out1, out2);
    } else if (ws_size >= WS_B) {
        // Tier B: round-3 proven path (+ fast hist & merged finalize).
        uint8_t* ws = (uint8_t*)d_ws;
        uint32_t* keyWS  = (uint32_t*)ws;
        uint16_t* idxWS  = (uint16_t*)(ws + KEY_BYTES);
        uint32_t* histWS = (uint32_t*)(ws + KEY_BYTES + IDX_BYTES);
        uint32_t* keyOUT = (uint32_t*)out0;
        uint16_t* idxOUT = (uint16_t*)out1;

        hist4_fast<<<g, b, 0, stream>>>(wts, histWS);
        scatter_tile<0,  true,  false><<<g, b, 0, stream>>>(wts, nullptr, nullptr, keyWS, idxWS, nullptr, nullptr, histWS);
        scatter_tile<8,  false, false><<<g, b, 0, stream>>>(wts, keyWS, idxWS, keyOUT, idxOUT, nullptr, nullptr, histWS);
        scatter_tile<16, false, false><<<g, b, 0, stream>>>(wts, keyOUT, idxOUT, keyWS, idxWS, nullptr, nullptr, histWS);
        scatter_tile<24, false, true ><<<g, b, 0, stream>>>(wts, keyWS, idxWS, nullptr, nullptr, (uint32_t*)out0, out1, histWS);
        finalize_row<<<g, b, 0, stream>>>(out0, out1, out2);
    } else {
        // Tier C: no-workspace fallback.
        uint32_t* bufA = (uint32_t*)out0;
        uint32_t* bufB = (uint32_t*)out1;
        radix_pass_fb<0 ><<<g, b, 0, stream>>>(wts, nullptr, bufA);
        radix_pass_fb<8 ><<<g, b, 0, stream>>>(wts, bufA, bufB);
        radix_pass_fb<16><<<g, b, 0, stream>>>(wts, bufB, bufA);
        radix_pass_fb<24><<<g, b, 0, stream>>>(wts, bufA, bufB);
        finalize_fb<<<g, b, 0, stream>>>(wts, bufB, out0, out1, out2);
    }
}

// Round 8
// 626.848 us; speedup vs baseline: 1.1146x; 1.1146x over previous
//
#include <hip/hip_runtime.h>
#include <stdint.h>

#define B    512
#define N    50257
#define BLK  512
#define NWAVE 8
#define TILE 5632            // stage 44 KB; raw LDS 50192 -> alloc 50688 -> 3 blocks/CU
#define CHUNK 704            // per-wave contiguous chunk = TILE/NWAVE
#define NGRP 11              // 64-elem groups per chunk
#define THRESH 0.4f

// Softmax weights are strictly positive floats: raw bit pattern is monotone
// in value. Complement -> ascending stable order == descending weight order,
// ties broken by ascending original index (stable LSD radix), matching
// jnp.argsort(-weights).
__device__ __forceinline__ uint32_t sort_key(float w) { return ~__float_as_uint(w); }

__device__ __forceinline__ void hist_elem(uint32_t* hw0, const float w) {
    const uint32_t key = sort_key(w);
    atomicAdd(hw0 + (key & 255u), 1u);
    atomicAdd(hw0 + 256 + ((key >> 8) & 255u), 1u);
    atomicAdd(hw0 + 512 + ((key >> 16) & 255u), 1u);
    atomicAdd(hw0 + 768 + ((key >> 24) & 255u), 1u);
}

// ---------------------------------------------------------------------------
// Shared: histogram kernel (per-wave-private bins, plain LDS atomics,
// float4-vectorized sweep).
// ---------------------------------------------------------------------------
__global__ __launch_bounds__(BLK) void hist4_fast(const float* __restrict__ wts,
                                                  uint32_t* __restrict__ histWS) {
    __shared__ uint32_t hw[NWAVE][4][256];   // 32 KB
    __shared__ uint32_t wtot[4];
    const int row = blockIdx.x;
    const size_t base = (size_t)row * N;
    const int tid = threadIdx.x;
    const int lane = tid & 63;
    const int wv = tid >> 6;

    {   // zero own wave's slice (no cross-wave access -> no barrier needed)
        uint32_t* p = &hw[wv][0][0];
        for (int j = lane; j < 4 * 256; j += 64) p[j] = 0;
    }
    uint32_t* hw0 = &hw[wv][0][0];

    // vectorized sweep (order-independent): head to 16B alignment, f4 body, tail
    const int head = (int)((4 - (base & 3)) & 3);
    for (int i = tid; i < head; i += BLK) hist_elem(hw0, wts[base + i]);
    const int nvec = (N - head) >> 2;
    const float4* v4 = (const float4*)(wts + base + head);
    for (int iv = tid; iv < nvec; iv += BLK) {
        const float4 f = v4[iv];
        hist_elem(hw0, f.x); hist_elem(hw0, f.y);
        hist_elem(hw0, f.z); hist_elem(hw0, f.w);
    }
    for (int i = head + 4 * nvec + tid; i < N; i += BLK) hist_elem(hw0, wts[base + i]);
    __syncthreads();

    for (int p = 0; p < 4; ++p) {
        uint32_t cnt = 0;
        if (tid < 256) {
            #pragma unroll
            for (int w = 0; w < NWAVE; ++w) cnt += hw[w][p][tid];
        }
        // exclusive scan over 256 bins: intra-wave shfl + cross-wave via wtot
        uint32_t incl = cnt;
        #pragma unroll
        for (int o = 1; o < 64; o <<= 1) {
            const uint32_t u = __shfl_up(incl, o);
            if (lane >= o) incl += u;
        }
        if (tid < 256 && lane == 63) wtot[tid >> 6] = incl;
        __syncthreads();
        if (tid < 256) {
            uint32_t prefix = 0;
            const int w4 = tid >> 6;
            #pragma unroll
            for (int w2 = 0; w2 < 4; ++w2) if (w2 < w4) prefix += wtot[w2];
            histWS[((size_t)row * 4 + p) * 256 + tid] = prefix + incl - cnt;
        }
        __syncthreads();   // protect wtot reuse
    }
}

// ---------------------------------------------------------------------------
// TIER A: software-pipelined wave-private scatter on packed u64 (key<<16|idx).
// TILE=5632 + u16 waveCnt: raw LDS 50192 (alloc 50688) -> 3 blocks/CU by LDS.
// launch_bounds stays (512,4): registers unconstrained, occupancy LDS-driven.
// Prefetch for tile t+1 issues AFTER the layout barrier (round-5 proven spot;
// issuing earlier broke L2/L3 producer->consumer reuse, r6).
// ---------------------------------------------------------------------------
template <int SHIFT, bool FIRST, bool LAST>
__global__ __launch_bounds__(BLK, 4) void scatter_pl(const float* __restrict__ wts,
                                                     const unsigned long long* __restrict__ src,
                                                     unsigned long long* __restrict__ dst,
                                                     uint32_t* __restrict__ outIdx,
                                                     float* __restrict__ outW,
                                                     const uint32_t* __restrict__ histWS) {
    __shared__ __align__(16) unsigned long long stage[TILE];  // 44 KB
    __shared__ uint16_t waveCnt[NWAVE][256];                  //  4 KB
    __shared__ uint32_t delta[256];                           //  1 KB
    __shared__ uint32_t wtot[4];

    const int row = blockIdx.x;
    const size_t base = (size_t)row * N;
    const int tid  = threadIdx.x;
    const int lane = tid & 63;
    const int wv   = tid >> 6;
    constexpr int PASS = SHIFT / 8;
    constexpr int KS = SHIFT + 16;   // digit position within packed pair

    uint32_t curReg = 0;             // this thread's bucket cursor (tid<256)
    if (tid < 256) curReg = histWS[((size_t)row * 4 + PASS) * 256 + tid];

    const int numTiles = (N + TILE - 1) / TILE;   // 9

    unsigned long long pairN[NGRP];
    {   // prefetch tile 0 (always full: TILE < N)
        const int cb = wv * CHUNK;
        #pragma unroll
        for (int g = 0; g < NGRP; ++g) {
            const int i = cb + g * 64 + lane;
            pairN[g] = FIRST ? (((unsigned long long)sort_key(wts[base + i]) << 16) | (uint32_t)i)
                             : src[base + i];
        }
    }

    for (int t = 0; t < numTiles; ++t) {
        const int tbase = t * TILE;
        const int tileLen = (N - tbase < TILE) ? (N - tbase) : TILE;
        const int cbase = tbase + wv * CHUNK;
        const bool full = (tbase + TILE <= N);

        // ---- Phase 1: rank own chunk from registers (NO barriers) ----
        // Safe to zero own waveCnt row here: phase 2 of tile t-1 finished
        // reading all rows before barrier (C,t-1) < (D,t-1).
        {   // 256 u16 = 512 B = 64 lanes x 8 B
            uint2* z = (uint2*)&waveCnt[wv][0];
            z[lane] = make_uint2(0u, 0u);
        }
        unsigned long long pairR[NGRP];
        uint32_t posR[NGRP];
        #pragma unroll
        for (int g = 0; g < NGRP; ++g) pairR[g] = pairN[g];

        if (full) {
            #pragma unroll
            for (int g = 0; g < NGRP; ++g) {
                const uint32_t d = (uint32_t)(pairR[g] >> KS) & 255u;
                unsigned long long peers = ~0ull;
                #pragma unroll
                for (int bb = 0; bb < 8; ++bb) {
                    const unsigned long long bit = __ballot((d >> bb) & 1u);
                    peers &= ((d >> bb) & 1u) ? bit : ~bit;
                }
                const unsigned long long lower = peers & ((1ull << lane) - 1ull);
                const uint32_t cnt = (uint32_t)waveCnt[wv][d];
                posR[g] = cnt + (uint32_t)__popcll(lower);
                if (lower == 0ull) waveCnt[wv][d] = (uint16_t)(cnt + (uint32_t)__popcll(peers));
            }
        } else {
            #pragma unroll
            for (int g = 0; g < NGRP; ++g) {
                const int i = cbase + g * 64 + lane;
                const bool valid = (i < N);
                const uint32_t d = (uint32_t)(pairR[g] >> KS) & 255u;
                unsigned long long peers = __ballot(valid);
                #pragma unroll
                for (int bb = 0; bb < 8; ++bb) {
                    const unsigned long long bit = __ballot((d >> bb) & 1u);
                    peers &= ((d >> bb) & 1u) ? bit : ~bit;
                }
                const unsigned long long lower = peers & ((1ull << lane) - 1ull);
                uint32_t cnt = 0;
                if (valid) cnt = (uint32_t)waveCnt[wv][d];
                posR[g] = cnt + (uint32_t)__popcll(lower);
                if (valid && lower == 0ull) waveCnt[wv][d] = (uint16_t)(cnt + (uint32_t)__popcll(peers));
            }
        }
        __syncthreads();                               // (A) ranks done; stage(t-1) drained

        // ---- Phase 2: tile layout (shfl scan, 2 barriers) ----
        uint32_t run = 0;
        if (tid < 256) {
            #pragma unroll
            for (int w = 0; w < NWAVE; ++w) {
                const uint32_t c = (uint32_t)waveCnt[w][tid];
                waveCnt[w][tid] = (uint16_t)run;       // excl offset across waves
                run += c;
            }
        }
        uint32_t incl = run;
        #pragma unroll
        for (int o = 1; o < 64; o <<= 1) {
            const uint32_t u = __shfl_up(incl, o);
            if (lane >= o) incl += u;
        }
        if (tid < 256 && lane == 63) wtot[tid >> 6] = incl;
        __syncthreads();                               // (B)
        if (tid < 256) {
            uint32_t prefix = 0;
            const int w4 = tid >> 6;
            #pragma unroll
            for (int w2 = 0; w2 < 4; ++w2) if (w2 < w4) prefix += wtot[w2];
            const uint32_t ts = prefix + incl - run;   // tileStart[tid]
            delta[tid] = curReg - ts;                  // global = delta[d] + p
            curReg += run;
            #pragma unroll
            for (int w = 0; w < NWAVE; ++w)
                waveCnt[w][tid] = (uint16_t)((uint32_t)waveCnt[w][tid] + ts);
        }
        __syncthreads();                               // (C) layout ready

        // ---- Prefetch next tile (latency hides under phases 3-4) ----
        if (t + 1 < numTiles) {
            const int ncb = (t + 1) * TILE + wv * CHUNK;
            if (ncb + CHUNK <= N) {                    // wave-uniform branch
                #pragma unroll
                for (int g = 0; g < NGRP; ++g) {
                    const int i = ncb + g * 64 + lane;
                    pairN[g] = FIRST ? (((unsigned long long)sort_key(wts[base + i]) << 16) | (uint32_t)i)
                                     : src[base + i];
                }
            } else {
                #pragma unroll
                for (int g = 0; g < NGRP; ++g) {
                    const int i = ncb + g * 64 + lane;
                    unsigned long long pair = 0;
                    if (i < N)
                        pair = FIRST ? (((unsigned long long)sort_key(wts[base + i]) << 16) | (uint32_t)i)
                                     : src[base + i];
                    pairN[g] = pair;
                }
            }
        }

        // ---- Phase 3: stage bucket-contiguous in LDS ----
        if (full) {
            #pragma unroll
            for (int g = 0; g < NGRP; ++g) {
                const uint32_t d = (uint32_t)(pairR[g] >> KS) & 255u;
                stage[(uint32_t)waveCnt[wv][d] + posR[g]] = pairR[g];
            }
        } else {
            #pragma unroll
            for (int g = 0; g < NGRP; ++g) {
                const int i = cbase + g * 64 + lane;
                if (i < N) {
                    const uint32_t d = (uint32_t)(pairR[g] >> KS) & 255u;
                    stage[(uint32_t)waveCnt[wv][d] + posR[g]] = pairR[g];
                }
            }
        }
        __syncthreads();                               // (D) stage complete

        // ---- Phase 4: 2-wide flush of contiguous runs to global ----
        const int tileLenEven = tileLen & ~1;
        for (int p0 = 2 * tid; p0 < tileLenEven; p0 += 2 * BLK) {
            const ulonglong2 two = *(const ulonglong2*)&stage[p0];   // 16B aligned
            const uint32_t d0 = (uint32_t)(two.x >> KS) & 255u;
            const uint32_t d1 = (uint32_t)(two.y >> KS) & 255u;
            const uint32_t g0 = delta[d0] + (uint32_t)p0;
            const uint32_t g1 = delta[d1] + (uint32_t)p0 + 1u;
            if (LAST) {
                outIdx[base + g0] = (uint32_t)(two.x & 0xFFFFull);
                outW[base + g0]   = __uint_as_float(~(uint32_t)(two.x >> 16));
                outIdx[base + g1] = (uint32_t)(two.y & 0xFFFFull);
                outW[base + g1]   = __uint_as_float(~(uint32_t)(two.y >> 16));
            } else {
                dst[base + g0] = two.x;
                dst[base + g1] = two.y;
            }
        }
        for (int p = tileLenEven + tid; p < tileLen; p += BLK) {     // odd tail
            const unsigned long long pair = stage[p];
            const uint32_t d = (uint32_t)(pair >> KS) & 255u;
            const uint32_t g = delta[d] + (uint32_t)p;
            if (LAST) {
                outIdx[base + g] = (uint32_t)(pair & 0xFFFFull);
                outW[base + g]   = __uint_as_float(~(uint32_t)(pair >> 16));
            } else {
                dst[base + g] = pair;
            }
        }
        // no trailing barrier: (A) of the next tile separates flush(t) reads
        // from stage(t+1) writes and delta(t+1) updates.
    }
}

// ---------------------------------------------------------------------------
// Shared: merged scan + normalize + idx->float (in place), block per row.
// out0 holds u32 idx, out1 holds sorted w on entry.
// ---------------------------------------------------------------------------
__global__ __launch_bounds__(BLK) void finalize_row(float* __restrict__ out0,
                                                    float* __restrict__ out1,
                                                    float* __restrict__ out2) {
    __shared__ float waveSum[NWAVE];
    __shared__ int   waveFirst[NWAVE];
    __shared__ float waveCum[NWAVE];
    __shared__ int   s_k;
    __shared__ float s_total;

    const int row = blockIdx.x;
    const size_t base = (size_t)row * N;
    const int tid  = threadIdx.x;
    const int lane = tid & 63;
    const int wv   = tid >> 6;

    if (tid == 0) { s_k = -1; s_total = 0.f; }
    __syncthreads();

    // Phase A: block-wide running cumsum with early exit
    float carry = 0.f;
    const int numTiles = (N + BLK - 1) / BLK;
    for (int t = 0; t < numTiles; ++t) {
        const int i = t * BLK + tid;
        const bool valid = (i < N);
        float w = valid ? out1[base + i] : 0.f;

        float s = w;
        #pragma unroll
        for (int o = 1; o < 64; o <<= 1) {
            float u = __shfl_up(s, o);
            if (lane >= o) s += u;
        }
        if (lane == 63) waveSum[wv] = s;
        __syncthreads();

        float prefix = 0.f, blockTot = 0.f;
        #pragma unroll
        for (int w2 = 0; w2 < NWAVE; ++w2) {
            float t2 = waveSum[w2];
            if (w2 < wv) prefix += t2;
            blockTot += t2;
        }
        const float cum = carry + prefix + s;

        const bool exceed = valid && (cum > THRESH);
        const unsigned long long bal = __ballot(exceed);
        const int fl = (bal == 0ull) ? 64 : (__ffsll(bal) - 1);
        if (lane == 0) waveFirst[wv] = fl;
        if (fl < 64 && lane == fl) waveCum[wv] = cum;
        __syncthreads();
        if (tid == 0) {
            for (int w2 = 0; w2 < NWAVE; ++w2) {
                if (waveFirst[w2] < 64) {
                    s_k = t * BLK + w2 * 64 + waveFirst[w2] + 1;
                    s_total = waveCum[w2];
                    break;
                }
            }
        }
        __syncthreads();
        if (s_k >= 0) break;
        carry += blockTot;
        __syncthreads();
    }

    int k = s_k;
    float total = s_total;
    if (k < 0) { k = N; total = carry; }
    const float inv = 1.0f / total;

    // Phase B: in-place convert + normalize, vectorized 16B (per-thread
    // read-before-write on identical addresses -> safe).
    const uint32_t* idxU = (const uint32_t*)out0;
    const int head = (int)((4 - (base & 3)) & 3);     // to 16B alignment
    const int nvec = (N - head) >> 2;
    const int vend = head + 4 * nvec;

    for (int i = tid; i < head; i += BLK) {           // head (<4 elems)
        const uint32_t idx = idxU[base + i];
        const float w = out1[base + i];
        out0[base + i] = (float)idx;
        out1[base + i] = (i < k) ? (w * inv) : 0.f;
    }
    const uint4*  ivp = (const uint4*)(idxU + base + head);
    float4*       o0v = (float4*)(out0 + base + head);
    float4*       o1v = (float4*)(out1 + base + head);
    for (int v = tid; v < nvec; v += BLK) {
        const uint4  iv = ivp[v];
        const float4 wv4 = o1v[v];
        const int i = head + 4 * v;
        float4 o0, o1;
        o0.x = (float)iv.x; o0.y = (float)iv.y; o0.z = (float)iv.z; o0.w = (float)iv.w;
        o1.x = (i + 0 < k) ? wv4.x * inv : 0.f;
        o1.y = (i + 1 < k) ? wv4.y * inv : 0.f;
        o1.z = (i + 2 < k) ? wv4.z * inv : 0.f;
        o1.w = (i + 3 < k) ? wv4.w * inv : 0.f;
        o0v[v] = o0;
        o1v[v] = o1;
    }
    for (int i = vend + tid; i < N; i += BLK) {       // tail (<4 elems)
        const uint32_t idx = idxU[base + i];
        const float w = out1[base + i];
        out0[base + i] = (float)idx;
        out1[base + i] = (i < k) ? (w * inv) : 0.f;
    }
    if (tid == 0) out2[row] = (float)k;
}

// ---------------------------------------------------------------------------
// TIER B (round-3 proven): subtile-ballot scatter on separate key/idx arrays.
// ---------------------------------------------------------------------------
#define NSUB (TILE / BLK)   // 11

template <int SHIFT, bool FIRST, bool LAST>
__global__ __launch_bounds__(BLK, 4) void scatter_tile(const float* __restrict__ wts,
                                                       const uint32_t* __restrict__ keySrc,
                                                       const uint16_t* __restrict__ idxSrc,
                                                       uint32_t* __restrict__ keyDst,
                                                       uint16_t* __restrict__ idxDst,
                                                       uint32_t* __restrict__ outIdx,
                                                       float* __restrict__ outW,
                                                       const uint32_t* __restrict__ histWS) {
    __shared__ uint32_t stageKey[TILE];
    __shared__ uint16_t stageIdx[TILE];
    __shared__ uint32_t waveCnt32[NWAVE][256];
    __shared__ uint16_t subOff[NSUB][256];
    __shared__ uint32_t cursor[256];
    __shared__ uint32_t tileCnt[256];
    __shared__ uint32_t tileStart[256];
    __shared__ uint32_t scanb[256];

    const int row = blockIdx.x;
    const size_t base = (size_t)row * N;
    const int tid  = threadIdx.x;
    const int lane = tid & 63;
    const int wv   = tid >> 6;
    constexpr int PASS = SHIFT / 8;

    if (tid < 256) cursor[tid] = histWS[((size_t)row * 4 + PASS) * 256 + tid];

    const int numTiles = (N + TILE - 1) / TILE;
    for (int t = 0; t < numTiles; ++t) {
        const int tbase = t * TILE;
        const int tileLen = (N - tbase < TILE) ? (N - tbase) : TILE;

        uint32_t keyR[NSUB];
        uint32_t idxR[NSUB];
        uint32_t posR[NSUB];

        #pragma unroll
        for (int s = 0; s < NSUB; ++s) {
            for (int j = tid; j < NWAVE * 256; j += BLK) ((uint32_t*)waveCnt32)[j] = 0;
            __syncthreads();

            const int i = tbase + s * BLK + tid;
            const bool valid = (i < N);
            uint32_t key = 0, idx = 0, d = 0;
            if (valid) {
                if (FIRST) { key = sort_key(wts[base + i]); idx = (uint32_t)i; }
                else       { key = keySrc[base + i]; idx = (uint32_t)idxSrc[base + i]; }
                d = (key >> SHIFT) & 255u;
            }
            keyR[s] = key;
            if (!FIRST) idxR[s] = idx;

            unsigned long long peers = __ballot(valid);
            #pragma unroll
            for (int b = 0; b < 8; ++b) {
                unsigned long long bit = __ballot(valid && ((d >> b) & 1u));
                peers &= ((d >> b) & 1u) ? bit : ~bit;
            }
            const unsigned long long lower = peers & ((1ull << lane) - 1ull);
            const uint32_t rank = (uint32_t)__popcll(lower);
            if (valid && lower == 0ull) waveCnt32[wv][d] = (uint32_t)__popcll(peers);
            __syncthreads();

            if (tid < 256) {
                uint32_t x = 0;
                #pragma unroll
                for (int w = 0; w < NWAVE; ++w) {
                    uint32_t c = waveCnt32[w][tid];
                    waveCnt32[w][tid] = x;
                    x += c;
                }
                subOff[s][tid] = (uint16_t)x;
            }
            __syncthreads();

            posR[s] = valid ? (waveCnt32[wv][d] + rank) : 0u;
            __syncthreads();
        }

        if (tid < 256) {
            uint32_t run = 0;
            #pragma unroll
            for (int s = 0; s < NSUB; ++s) {
                uint32_t c = subOff[s][tid];
                subOff[s][tid] = (uint16_t)run;
                run += c;
            }
            tileCnt[tid] = run;
            scanb[tid] = run;
        }
        __syncthreads();
        for (int off = 1; off < 256; off <<= 1) {
            uint32_t add = 0;
            if (tid < 256 && tid >= off) add = scanb[tid - off];
            __syncthreads();
            if (tid < 256) scanb[tid] += add;
            __syncthreads();
        }
        if (tid < 256) tileStart[tid] = (tid == 0) ? 0u : scanb[tid - 1];
        __syncthreads();

        #pragma unroll
        for (int s = 0; s < NSUB; ++s) {
            const int i = tbase + s * BLK + tid;
            if (i < N) {
                const uint32_t d = (keyR[s] >> SHIFT) & 255u;
                const uint32_t pos = tileStart[d] + (uint32_t)subOff[s][d] + posR[s];
                stageKey[pos] = keyR[s];
                stageIdx[pos] = (uint16_t)(FIRST ? (uint32_t)i : idxR[s]);
            }
        }
        __syncthreads();

        for (int p = tid; p < tileLen; p += BLK) {
            const uint32_t k = stageKey[p];
            const uint32_t d = (k >> SHIFT) & 255u;
            const uint32_t g = cursor[d] + (uint32_t)p - tileStart[d];
            if (LAST) {
                outIdx[base + g] = (uint32_t)stageIdx[p];
                outW[base + g]   = __uint_as_float(~k);
            } else {
                keyDst[base + g] = k;
                idxDst[base + g] = stageIdx[p];
            }
        }
        __syncthreads();
        if (tid < 256) cursor[tid] += tileCnt[tid];
        __syncthreads();
    }
}

// ---------------------------------------------------------------------------
// TIER C (round-1 proven): gather-based fallback, no workspace.
// ---------------------------------------------------------------------------
template <int SHIFT>
__global__ __launch_bounds__(BLK) void radix_pass_fb(const float* __restrict__ wts,
                                                     const uint32_t* __restrict__ src,
                                                     uint32_t* __restrict__ dst) {
    __shared__ uint32_t hist[256];
    __shared__ uint32_t scanb[256];
    __shared__ uint32_t running[256];
    __shared__ uint32_t waveCnt32[NWAVE][256];

    const int row = blockIdx.x;
    const size_t base = (size_t)row * N;
    const int tid  = threadIdx.x;
    const int lane = tid & 63;
    const int wv   = tid >> 6;

    if (tid < 256) hist[tid] = 0;
    __syncthreads();
    for (int i = tid; i < N; i += BLK) {
        uint32_t idx = (SHIFT == 0) ? (uint32_t)i : src[base + i];
        uint32_t d = (sort_key(wts[base + idx]) >> SHIFT) & 255u;
        atomicAdd(&hist[d], 1u);
    }
    __syncthreads();

    if (tid < 256) scanb[tid] = hist[tid];
    __syncthreads();
    for (int off = 1; off < 256; off <<= 1) {
        uint32_t add = 0;
        if (tid < 256 && tid >= off) add = scanb[tid - off];
        __syncthreads();
        if (tid < 256) scanb[tid] += add;
        __syncthreads();
    }
    if (tid < 256) running[tid] = (tid == 0) ? 0u : scanb[tid - 1];
    __syncthreads();

    const int numTiles = (N + BLK - 1) / BLK;
    for (int t = 0; t < numTiles; ++t) {
        for (int j = tid; j < NWAVE * 256; j += BLK) ((uint32_t*)waveCnt32)[j] = 0;
        __syncthreads();

        const int i = t * BLK + tid;
        const bool valid = (i < N);
        uint32_t idx = 0, d = 0;
        if (valid) {
            idx = (SHIFT == 0) ? (uint32_t)i : src[base + i];
            d = (sort_key(wts[base + idx]) >> SHIFT) & 255u;
        }
        unsigned long long peers = __ballot(valid);
        #pragma unroll
        for (int b = 0; b < 8; ++b) {
            unsigned long long bit = __ballot(valid && ((d >> b) & 1u));
            peers &= ((d >> b) & 1u) ? bit : ~bit;
        }
        const unsigned long long lower = peers & ((1ull << lane) - 1ull);
        const uint32_t rank = (uint32_t)__popcll(lower);
        if (valid && lower == 0ull) waveCnt32[wv][d] = (uint32_t)__popcll(peers);
        __syncthreads();

        if (tid < 256) {
            uint32_t s = running[tid];
            #pragma unroll
            for (int w = 0; w < NWAVE; ++w) {
                uint32_t c = waveCnt32[w][tid];
                waveCnt32[w][tid] = s;
                s += c;
            }
            running[tid] = s;
        }
        __syncthreads();

        if (valid) {
            uint32_t pos = waveCnt32[wv][d] + rank;
            dst[base + pos] = idx;
        }
        __syncthreads();
    }
}

__global__ __launch_bounds__(BLK) void finalize_fb(const float* __restrict__ wts,
                                                   const uint32_t* __restrict__ sidx,
                                                   float* __restrict__ out0,
                                                   float* __restrict__ out1,
                                                   float* __restrict__ out2) {
    __shared__ float waveSum[NWAVE];
    __shared__ int   waveFirst[NWAVE];
    __shared__ float waveCum[NWAVE];
    __shared__ int   s_k;
    __shared__ float s_total;

    const int row = blockIdx.x;
    const size_t base = (size_t)row * N;
    const int tid  = threadIdx.x;
    const int lane = tid & 63;
    const int wv   = tid >> 6;

    if (tid == 0) { s_k = -1; s_total = 0.f; }
    __syncthreads();

    float carry = 0.f;
    const int numTiles = (N + BLK - 1) / BLK;
    for (int t = 0; t < numTiles; ++t) {
        const int i = t * BLK + tid;
        const bool valid = (i < N);
        float w = valid ? wts[base + sidx[base + i]] : 0.f;

        float s = w;
        #pragma unroll
        for (int o = 1; o < 64; o <<= 1) {
            float u = __shfl_up(s, o);
            if (lane >= o) s += u;
        }
        if (lane == 63) waveSum[wv] = s;
        __syncthreads();

        float prefix = 0.f, blockTot = 0.f;
        #pragma unroll
        for (int w2 = 0; w2 < NWAVE; ++w2) {
            float t2 = waveSum[w2];
            if (w2 < wv) prefix += t2;
            blockTot += t2;
        }
        const float cum = carry + prefix + s;

        const bool exceed = valid && (cum > THRESH);
        const unsigned long long bal = __ballot(exceed);
        const int fl = (bal == 0ull) ? 64 : (__ffsll(bal) - 1);
        if (lane == 0) waveFirst[wv] = fl;
        if (fl < 64 && lane == fl) waveCum[wv] = cum;
        __syncthreads();
        if (tid == 0) {
            for (int w2 = 0; w2 < NWAVE; ++w2) {
                if (waveFirst[w2] < 64) {
                    s_k = t * BLK + w2 * 64 + waveFirst[w2] + 1;
                    s_total = waveCum[w2];
                    break;
                }
            }
        }
        __syncthreads();
        if (s_k >= 0) break;
        carry += blockTot;
        __syncthreads();
    }

    int k = s_k;
    float total = s_total;
    if (k < 0) { k = N; total = carry; }

    for (int i = tid; i < N; i += BLK) {
        const uint32_t idx = sidx[base + i];
        const float w = wts[base + idx];
        out0[base + i] = (float)idx;
        out1[base + i] = (i < k) ? (w / total) : 0.f;
    }
    if (tid == 0) out2[row] = (float)k;
}

// ---------------------------------------------------------------------------

extern "C" void kernel_launch(void* const* d_in, const int* in_sizes, int n_in,
                              void* d_out, int out_size, void* d_ws, size_t ws_size,
                              hipStream_t stream) {
    const float* wts = (const float*)d_in[0];
    float* out0 = (float*)d_out;                       // sorted_idx (as f32)
    float* out1 = out0 + (size_t)B * N;                // norm_w
    float* out2 = out0 + 2 * (size_t)B * N;            // k (as f32)

    const size_t PAIR_BYTES = (size_t)B * N * 8;       // 205,852,672
    const size_t KEY_BYTES  = (size_t)B * N * 4;
    const size_t IDX_BYTES  = (size_t)B * N * 2;
    const size_t HIST_BYTES = (size_t)B * 4 * 256 * 4; // 2,097,152
    const size_t WS_A = PAIR_BYTES + HIST_BYTES;
    const size_t WS_B = KEY_BYTES + IDX_BYTES + HIST_BYTES;

    dim3 g(B), b(BLK);
    if (ws_size >= WS_A) {
        // Tier A: pipelined packed-u64 wave-private path.
        uint8_t* ws = (uint8_t*)d_ws;
        unsigned long long* pairWS  = (unsigned long long*)ws;
        uint32_t*           histWS  = (uint32_t*)(ws + PAIR_BYTES);
        unsigned long long* pairOUT = (unsigned long long*)d_out;  // 206MB in d_out

        hist4_fast<<<g, b, 0, stream>>>(wts, histWS);
        scatter_pl<0,  true,  false><<<g, b, 0, stream>>>(wts, nullptr, pairWS, nullptr, nullptr, histWS);
        scatter_pl<8,  false, false><<<g, b, 0, stream>>>(nullptr, pairWS, pairOUT, nullptr, nullptr, histWS);
        scatter_pl<16, false, false><<<g, b, 0, stream>>>(nullptr, pairOUT, pairWS, nullptr, nullptr, histWS);
        scatter_pl<24, false, true ><<<g, b, 0, stream>>>(nullptr, pairWS, nullptr, (uint32_t*)out0, out1, histWS);
        finalize_row<<<g, b, 0, stream>>>(out0, out1, out2);
    } else if (ws_size >= WS_B) {
        // Tier B: round-3 proven path (+ fast hist & merged finalize).
        uint8_t* ws = (uint8_t*)d_ws;
        uint32_t* keyWS  = (uint32_t*)ws;
        uint16_t* idxWS  = (uint16_t*)(ws + KEY_BYTES);
        uint32_t* histWS = (uint32_t*)(ws + KEY_BYTES + IDX_BYTES);
        uint32_t* keyOUT = (uint32_t*)out0;
        uint16_t* idxOUT = (uint16_t*)out1;

        hist4_fast<<<g, b, 0, stream>>>(wts, histWS);
        scatter_tile<0,  true,  false><<<g, b, 0, stream>>>(wts, nullptr, nullptr, keyWS, idxWS, nullptr, nullptr, histWS);
        scatter_tile<8,  false, false><<<g, b, 0, stream>>>(wts, keyWS, idxWS, keyOUT, idxOUT, nullptr, nullptr, histWS);
        scatter_tile<16, false, false><<<g, b, 0, stream>>>(wts, keyOUT, idxOUT, keyWS, idxWS, nullptr, nullptr, histWS);
        scatter_tile<24, false, true ><<<g, b, 0, stream>>>(wts, keyWS, idxWS, nullptr, nullptr, (uint32_t*)out0, out1, histWS);
        finalize_row<<<g, b, 0, stream>>>(out0, out1, out2);
    } else {
        // Tier C: no-workspace fallback.
        uint32_t* bufA = (uint32_t*)out0;
        uint32_t* bufB = (uint32_t*)out1;
        radix_pass_fb<0 ><<<g, b, 0, stream>>>(wts, nullptr, bufA);
        radix_pass_fb<8 ><<<g, b, 0, stream>>>(wts, bufA, bufB);
        radix_pass_fb<16><<<g, b, 0, stream>>>(wts, bufB, bufA);
        radix_pass_fb<24><<<g, b, 0, stream>>>(wts, bufA, bufB);
        finalize_fb<<<g, b, 0, stream>>>(wts, bufB, out0, out1, out2);
    }
}